// Round 4
// baseline (1396.885 us; speedup 1.0000x reference)
//
#include <hip/hip_runtime.h>
#include <stdint.h>

typedef unsigned short u16;
typedef float f32x4 __attribute__((ext_vector_type(4)));
typedef short bf16x8 __attribute__((ext_vector_type(8)));

// ---------- helpers ----------
__device__ __forceinline__ u16 f2bu(float f) {           // fp32 -> bf16 (RNE)
  uint32_t x = __builtin_bit_cast(uint32_t, f);
  x += 0x7fffu + ((x >> 16) & 1u);
  return (u16)(x >> 16);
}
__device__ __forceinline__ float b2f(u16 u) {            // bf16 -> fp32 (exact)
  return __builtin_bit_cast(float, (uint32_t)u << 16);
}
__device__ __forceinline__ void gll16(const void* g, void* l) {
  __builtin_amdgcn_global_load_lds(
      (const __attribute__((address_space(1))) void*)g,
      (__attribute__((address_space(3))) void*)l, 16, 0, 0);
}
#define MEMFENCE asm volatile("" ::: "memory")

// ---------- fp32 -> bf16 convert ----------
__global__ __launch_bounds__(256) void cvt_f32_bf16_kernel(
    const float* __restrict__ in, u16* __restrict__ out, int n4) {
  int i = blockIdx.x * 256 + threadIdx.x;
  const int stride = gridDim.x * 256;
  for (; i < n4; i += stride) {
    float4 f = reinterpret_cast<const float4*>(in)[i];
    ushort4 o;
    o.x = f2bu(f.x); o.y = f2bu(f.y); o.z = f2bu(f.z); o.w = f2bu(f.w);
    reinterpret_cast<ushort4*>(out)[i] = o;
  }
}

// ---------- 256x256 GEMM, BK=32, 8 waves, 4-buffer, 2-phase/K-tile ----------
// C[m,n] = sum_k A[m,k]*B[n,k] + bias[n], bf16 in/out, fp32 accum.
// Per K-tile: phase0 {8 ds_read (a0-3,b0-3) | stage A(t+3) | bar | 16 MFMA | bar}
//             phase1 {4 ds_read (a4-7)      | stage B(t+3) | vmcnt(8) | bar | 16 MFMA | bar}
// vmcnt certifies tile t+1 one barrier before its first read; never 0 except tail.
__global__ __launch_bounds__(512, 2) void gemm256_bt_bias(
    const u16* __restrict__ A, const u16* __restrict__ Bw,
    const float* __restrict__ bias, u16* __restrict__ C,
    int N, int K, int ntn) {
  __shared__ u16 lds[4][2][8192];   // [buf][A=0/B=1][256 rows * 32 cols]
  const int tid = threadIdx.x;
  const int lane = tid & 63, wid = tid >> 6;
  const int wr = wid >> 2, wc = wid & 3;        // wave grid 2 (M) x 4 (N)
  const int fr = lane & 15, kg = lane >> 4;

  // XCD-aware swizzle (grid % 8 == 0 for both calls)
  const int cpx = (int)gridDim.x >> 3;
  const int bid = blockIdx.x;
  const int sid = (bid & 7) * cpx + (bid >> 3);
  const int mt = sid / ntn, nt = sid % ntn;

  // staging: flat slot s = tid (+512 for 2nd round); row = s>>2, col8 = s&3.
  // source col8 pre-swizzled: col8' = col8 ^ ((row>>1)&3)
  const int srow = tid >> 2;                    // 0..127 (round 1 adds 128)
  const int scol = (tid & 3) ^ ((tid >> 3) & 3);
  const u16* Ag = A + (size_t)(mt * 256 + srow) * K + scol * 8;
  const u16* Bg = Bw + (size_t)(nt * 256 + srow) * K + scol * 8;
  const size_t rstep = (size_t)128 * K;

  // fragment read offsets (u16 units), swizzled to match source permutation
  const int sw = (fr >> 1) & 3;
  const int aoff = (wr * 128 + fr) * 32 + (kg ^ sw) * 8;
  const int boff = (wc * 64 + fr) * 32 + (kg ^ sw) * 8;

  f32x4 acc[8][4];
#pragma unroll
  for (int i = 0; i < 8; i++)
#pragma unroll
    for (int j = 0; j < 4; j++) acc[i][j] = f32x4{0.f, 0.f, 0.f, 0.f};

  const int NT = K >> 5;

#define STAGE_A(b, kt) do {                                 \
    const u16* a_ = Ag + (size_t)(kt) * 32;                 \
    gll16(a_,         &lds[(b)][0][wid * 512]);             \
    gll16(a_ + rstep, &lds[(b)][0][4096 + wid * 512]);      \
  } while (0)
#define STAGE_B(b, kt) do {                                 \
    const u16* b_ = Bg + (size_t)(kt) * 32;                 \
    gll16(b_,         &lds[(b)][1][wid * 512]);             \
    gll16(b_ + rstep, &lds[(b)][1][4096 + wid * 512]);      \
  } while (0)

  STAGE_A(0, 0); STAGE_B(0, 0);
  STAGE_A(1, 1); STAGE_B(1, 1);
  STAGE_A(2, 2); STAGE_B(2, 2);
  asm volatile("s_waitcnt vmcnt(8)" ::: "memory");   // tile 0 landed
  __builtin_amdgcn_s_barrier();
  MEMFENCE;

  for (int t = 0; t < NT; t++) {
    const u16* As = &lds[t & 3][0][0];
    const u16* Bs = &lds[t & 3][1][0];

    // -------- phase 0: b0-b3 + a0-a3, MFMA rows 0-63 --------
    bf16x8 bv[4], af[4];
#pragma unroll
    for (int nj = 0; nj < 4; nj++)
      bv[nj] = *(const bf16x8*)&Bs[boff + nj * 512];
#pragma unroll
    for (int mi = 0; mi < 4; mi++)
      af[mi] = *(const bf16x8*)&As[aoff + mi * 512];
    if (t + 3 < NT) STAGE_A((t + 3) & 3, t + 3);
    __builtin_amdgcn_s_barrier();
    MEMFENCE;
    __builtin_amdgcn_s_setprio(1);
#pragma unroll
    for (int mi = 0; mi < 4; mi++)
#pragma unroll
      for (int nj = 0; nj < 4; nj++)
        acc[mi][nj] = __builtin_amdgcn_mfma_f32_16x16x32_bf16(
            af[mi], bv[nj], acc[mi][nj], 0, 0, 0);
    __builtin_amdgcn_s_setprio(0);
    __builtin_amdgcn_s_barrier();
    MEMFENCE;

    // -------- phase 1: a4-a7, MFMA rows 64-127 --------
    bf16x8 ag[4];
#pragma unroll
    for (int mi = 0; mi < 4; mi++)
      ag[mi] = *(const bf16x8*)&As[aoff + 2048 + mi * 512];
    if (t + 3 < NT) STAGE_B((t + 3) & 3, t + 3);
    // certify tile t+1 (oldest 4 outstanding loads) before its first read
    if (t <= NT - 4)      asm volatile("s_waitcnt vmcnt(8)" ::: "memory");
    else if (t == NT - 3) asm volatile("s_waitcnt vmcnt(4)" ::: "memory");
    else if (t == NT - 2) asm volatile("s_waitcnt vmcnt(0)" ::: "memory");
    __builtin_amdgcn_s_barrier();
    MEMFENCE;
    __builtin_amdgcn_s_setprio(1);
#pragma unroll
    for (int mi = 0; mi < 4; mi++)
#pragma unroll
      for (int nj = 0; nj < 4; nj++)
        acc[4 + mi][nj] = __builtin_amdgcn_mfma_f32_16x16x32_bf16(
            ag[mi], bv[nj], acc[4 + mi][nj], 0, 0, 0);
    __builtin_amdgcn_s_setprio(0);
    if (t < NT - 1) {
      __builtin_amdgcn_s_barrier();   // iteration boundary
      MEMFENCE;
    }
  }
#undef STAGE_A
#undef STAGE_B

  // C/D layout per 16x16 frag: col = lane&15, row = (lane>>4)*4 + reg
  const int crow0 = mt * 256 + wr * 128 + kg * 4;
  const int ccol0 = nt * 256 + wc * 64 + fr;
#pragma unroll
  for (int nj = 0; nj < 4; nj++) {
    const int col = ccol0 + nj * 16;
    const float bb = bias[col];
#pragma unroll
    for (int mi = 0; mi < 8; mi++) {
      const int r0 = crow0 + mi * 16;
      f32x4 v = acc[mi][nj];
#pragma unroll
      for (int r = 0; r < 4; r++)
        C[(size_t)(r0 + r) * N + col] = f2bu(v[r] + bb);
    }
  }
}

// ---------- tiny attention: S=3, 16 heads of d=64 ----------
__global__ __launch_bounds__(256) void attn3_kernel(
    const u16* __restrict__ qkv, u16* __restrict__ ctx) {
  const int tid = threadIdx.x;
  const int lane = tid & 63, wid = tid >> 6;
  const int unit = blockIdx.x * 4 + wid;
  const int b = unit >> 2, hg = unit & 3;
  const size_t qbase = (size_t)b * 3 * 3072 + hg * 256 + lane * 4;

  float q[3][4], k[3][4], v[3][4];
#pragma unroll
  for (int s = 0; s < 3; s++) {
    ushort4 uq = *(const ushort4*)(qkv + qbase + (size_t)s * 3072);
    ushort4 uk = *(const ushort4*)(qkv + qbase + (size_t)s * 3072 + 1024);
    ushort4 uv = *(const ushort4*)(qkv + qbase + (size_t)s * 3072 + 2048);
    q[s][0] = b2f(uq.x); q[s][1] = b2f(uq.y); q[s][2] = b2f(uq.z); q[s][3] = b2f(uq.w);
    k[s][0] = b2f(uk.x); k[s][1] = b2f(uk.y); k[s][2] = b2f(uk.z); k[s][3] = b2f(uk.w);
    v[s][0] = b2f(uv.x); v[s][1] = b2f(uv.y); v[s][2] = b2f(uv.z); v[s][3] = b2f(uv.w);
  }

  float sc[3][3];
#pragma unroll
  for (int i = 0; i < 3; i++)
#pragma unroll
    for (int j = 0; j < 3; j++) {
      float p = q[i][0] * k[j][0] + q[i][1] * k[j][1] +
                q[i][2] * k[j][2] + q[i][3] * k[j][3];
      p += __shfl_xor(p, 1);
      p += __shfl_xor(p, 2);
      p += __shfl_xor(p, 4);
      p += __shfl_xor(p, 8);   // 16-lane group = one head's 64 dims
      sc[i][j] = p;
    }

  float o[3][4];
#pragma unroll
  for (int i = 0; i < 3; i++) {
    float mx = fmaxf(sc[i][0], fmaxf(sc[i][1], sc[i][2]));
    float e0 = __expf((sc[i][0] - mx) * 0.125f);
    float e1 = __expf((sc[i][1] - mx) * 0.125f);
    float e2 = __expf((sc[i][2] - mx) * 0.125f);
    float inv = 1.f / (e0 + e1 + e2);
    e0 *= inv; e1 *= inv; e2 *= inv;
#pragma unroll
    for (int d = 0; d < 4; d++)
      o[i][d] = e0 * v[0][d] + e1 * v[1][d] + e2 * v[2][d];
  }

  const size_t obase = (size_t)b * 3 * 1024 + hg * 256 + lane * 4;
#pragma unroll
  for (int i = 0; i < 3; i++) {
    ushort4 ov;
    ov.x = f2bu(o[i][0]); ov.y = f2bu(o[i][1]);
    ov.z = f2bu(o[i][2]); ov.w = f2bu(o[i][3]);
    *(ushort4*)(ctx + obase + (size_t)i * 1024) = ov;
  }
}

// ---------- residual + LayerNorm: wave per row of 1024 ----------
__global__ __launch_bounds__(256) void ln_kernel(
    const float* __restrict__ slots, const u16* __restrict__ ao,
    const float* __restrict__ g, const float* __restrict__ bvec,
    float* __restrict__ out) {
  const int tid = threadIdx.x;
  const int lane = tid & 63, wid = tid >> 6;
  const int row = blockIdx.x * 4 + wid;
  const size_t rb = (size_t)row * 1024;

  float y[16];
  float sum = 0.f, sq = 0.f;
#pragma unroll
  for (int c = 0; c < 4; c++) {
    const int col = c * 256 + lane * 4;
    float4 sl = *(const float4*)(slots + rb + col);
    ushort4 a4 = *(const ushort4*)(ao + rb + col);
    float y0 = sl.x + b2f(a4.x), y1 = sl.y + b2f(a4.y);
    float y2 = sl.z + b2f(a4.z), y3 = sl.w + b2f(a4.w);
    y[c * 4 + 0] = y0; y[c * 4 + 1] = y1; y[c * 4 + 2] = y2; y[c * 4 + 3] = y3;
    sum += y0 + y1 + y2 + y3;
    sq += y0 * y0 + y1 * y1 + y2 * y2 + y3 * y3;
  }
#pragma unroll
  for (int m = 1; m < 64; m <<= 1) {
    sum += __shfl_xor(sum, m);
    sq  += __shfl_xor(sq, m);
  }
  const float mu = sum * (1.0f / 1024.0f);
  const float var = sq * (1.0f / 1024.0f) - mu * mu;
  const float rs = rsqrtf(var + 1e-5f);
#pragma unroll
  for (int c = 0; c < 4; c++) {
    const int col = c * 256 + lane * 4;
    float4 gg = *(const float4*)(g + col);
    float4 bb = *(const float4*)(bvec + col);
    float4 ov;
    ov.x = (y[c * 4 + 0] - mu) * rs * gg.x + bb.x;
    ov.y = (y[c * 4 + 1] - mu) * rs * gg.y + bb.y;
    ov.z = (y[c * 4 + 2] - mu) * rs * gg.z + bb.z;
    ov.w = (y[c * 4 + 3] - mu) * rs * gg.w + bb.w;
    *(float4*)(out + rb + col) = ov;
  }
}

extern "C" void kernel_launch(void* const* d_in, const int* in_sizes, int n_in,
                              void* d_out, int out_size, void* d_ws, size_t ws_size,
                              hipStream_t stream) {
  const float* slots = (const float*)d_in[0];
  const float* in_w  = (const float*)d_in[1];
  const float* in_b  = (const float*)d_in[2];
  const float* out_w = (const float*)d_in[3];
  const float* out_b = (const float*)d_in[4];
  const float* ln_g  = (const float*)d_in[5];
  const float* ln_b  = (const float*)d_in[6];
  float* out = (float*)d_out;

  const int M = 32768 * 3;  // 98304 rows

  // workspace layout (aliased):
  //   Abf   [M*1024 bf16] = 201,326,592 B   (later reused as ctx)
  //   Winb  [3072*1024]   =   6,291,456 B
  //   Woutb [1024*1024]   =   2,097,152 B
  //   qkv   [M*3072]      = 603,979,776 B   (first third later reused as attn_out)
  char* ws = (char*)d_ws;
  u16* Abf   = (u16*)ws;
  u16* Winb  = (u16*)(ws + 201326592);
  u16* Woutb = (u16*)(ws + 207618048);
  u16* qkv   = (u16*)(ws + 209715200);

  cvt_f32_bf16_kernel<<<2048, 256, 0, stream>>>(slots, Abf, M * 1024 / 4);
  cvt_f32_bf16_kernel<<<2048, 256, 0, stream>>>(in_w, Winb, 3072 * 1024 / 4);
  cvt_f32_bf16_kernel<<<1024, 256, 0, stream>>>(out_w, Woutb, 1024 * 1024 / 4);

  // qkv = Abf @ Winb^T + in_b : M x 3072, tiles 384 x 12
  gemm256_bt_bias<<<384 * 12, 512, 0, stream>>>(Abf, Winb, in_b, qkv, 3072, 1024, 12);

  // ctx (overwrites Abf)
  attn3_kernel<<<32768, 256, 0, stream>>>(qkv, Abf);

  // attn_out = ctx @ Woutb^T + out_b (overwrites start of qkv) : M x 1024, tiles 384 x 4
  gemm256_bt_bias<<<384 * 4, 512, 0, stream>>>(Abf, Woutb, out_b, qkv, 1024, 1024, 4);

  // out = LN(slots + attn_out) * g + b
  ln_kernel<<<M / 4, 256, 0, stream>>>(slots, qkv, ln_g, ln_b, out);
}

// Round 5
// 1359.976 us; speedup vs baseline: 1.0271x; 1.0271x over previous
//
#include <hip/hip_runtime.h>
#include <stdint.h>

typedef unsigned short u16;
typedef float f32x4 __attribute__((ext_vector_type(4)));
typedef short bf16x8 __attribute__((ext_vector_type(8)));

// ---------- helpers ----------
__device__ __forceinline__ u16 f2bu(float f) {           // fp32 -> bf16 (RNE)
  uint32_t x = __builtin_bit_cast(uint32_t, f);
  x += 0x7fffu + ((x >> 16) & 1u);
  return (u16)(x >> 16);
}
__device__ __forceinline__ float b2f(u16 u) {            // bf16 -> fp32 (exact)
  return __builtin_bit_cast(float, (uint32_t)u << 16);
}
__device__ __forceinline__ void gll16(const void* g, void* l) {
  __builtin_amdgcn_global_load_lds(
      (const __attribute__((address_space(1))) void*)g,
      (__attribute__((address_space(3))) void*)l, 16, 0, 0);
}
#define MEMFENCE asm volatile("" ::: "memory")
#define BAR() do { __builtin_amdgcn_s_barrier(); MEMFENCE; } while (0)

// ---------- fp32 -> bf16 convert ----------
__global__ __launch_bounds__(256) void cvt_f32_bf16_kernel(
    const float* __restrict__ in, u16* __restrict__ out, int n4) {
  int i = blockIdx.x * 256 + threadIdx.x;
  const int stride = gridDim.x * 256;
  for (; i < n4; i += stride) {
    float4 f = reinterpret_cast<const float4*>(in)[i];
    ushort4 o;
    o.x = f2bu(f.x); o.y = f2bu(f.y); o.z = f2bu(f.z); o.w = f2bu(f.w);
    reinterpret_cast<ushort4*>(out)[i] = o;
  }
}

// ---------- 256x256 GEMM, BK=64, 2 buf, 4 fine phases per K-step ----------
// C[m,n] = sum_k A[m,k]*B[n,k] + bias[n], bf16 in/out, fp32 accum.
// LDS [buf][op][khalf][256 rows x 32 k-cols]; half-tile = 16KB = 2 gll/wave.
// Per K-step t (buf=t&1): P0{rd A[kk0]x8,B01[kk0] | stage A-klo(t+1)} P1{B23[kk0] | B-klo}
//                         P2{rd A[kk1]x8,B01[kk1] | stage A-khi(t+1)} P3{B23[kk1] | B-khi}
// Each phase: reads/stage -> bar -> setprio(1) 16 MFMA setprio(0) -> [vmcnt] bar.
// Per-wave gll queue rotates [A-klo,B-klo,A-khi,B-khi]x2 -> vmcnt(4) at P1-close
// certifies {A-khi,B-khi}(t); at P3-close certifies {A-klo,B-klo}(t+1). Never 0
// except the tail. WAR: a buffer's reads drain (lgkm before MFMA) before the
// closing barrier that precedes any gll overwriting it.
__global__ __launch_bounds__(512, 2) void gemm256_bt_bias(
    const u16* __restrict__ A, const u16* __restrict__ Bw,
    const float* __restrict__ bias, u16* __restrict__ C,
    int N, int K, int ntn) {
  __shared__ u16 lds[2][2][2][8192];   // [buf][A=0/B=1][khalf][256*32]
  const int tid = threadIdx.x;
  const int lane = tid & 63, wid = tid >> 6;
  const int wr = wid >> 2, wc = wid & 3;        // wave grid 2 (M) x 4 (N)
  const int fr = lane & 15, kg = lane >> 4;

  // XCD-aware swizzle (grid % 8 == 0 for both calls)
  const int cpx = (int)gridDim.x >> 3;
  const int bid = blockIdx.x;
  const int sid = (bid & 7) * cpx + (bid >> 3);
  const int mt = sid / ntn, nt = sid % ntn;

  // staging source: slot s = j*512+tid -> row = s>>2, col8 = s&3 (16B slots,
  // 4 per 32-col half-row); source col8 pre-swizzled col8^((row>>1)&3).
  const int srow = tid >> 2;                    // + 128 for round j=1
  const int scol = (tid & 3) ^ ((tid >> 3) & 3);
  const u16* Ag = A + (size_t)(mt * 256 + srow) * K + scol * 8;
  const u16* Bg = Bw + (size_t)(nt * 256 + srow) * K + scol * 8;
  const size_t rstep = (size_t)128 * K;

  // fragment read offsets (u16), same swizzle on the read side
  const int sw = (fr >> 1) & 3;
  const int kgs = (kg ^ sw) * 8;
  const int aoff = (wr * 128 + fr) * 32 + kgs;
  const int boff = (wc * 64 + fr) * 32 + kgs;

  f32x4 acc[8][4];
#pragma unroll
  for (int i = 0; i < 8; i++)
#pragma unroll
    for (int j = 0; j < 4; j++) acc[i][j] = f32x4{0.f, 0.f, 0.f, 0.f};

  const int NT = K >> 6;

#define STAGE_A(kh, kt, nb) do {                               \
    const u16* s_ = Ag + (size_t)(kt) * 64 + (kh) * 32;        \
    gll16(s_,         &lds[nb][0][kh][wid * 512]);             \
    gll16(s_ + rstep, &lds[nb][0][kh][4096 + wid * 512]);      \
  } while (0)
#define STAGE_B(kh, kt, nb) do {                               \
    const u16* s_ = Bg + (size_t)(kt) * 64 + (kh) * 32;        \
    gll16(s_,         &lds[nb][1][kh][wid * 512]);             \
    gll16(s_ + rstep, &lds[nb][1][kh][4096 + wid * 512]);      \
  } while (0)

  // prologue: tile 0 into buf0; certify its k-lo halves
  STAGE_A(0, 0, 0); STAGE_B(0, 0, 0);
  STAGE_A(1, 0, 0); STAGE_B(1, 0, 0);
  asm volatile("s_waitcnt vmcnt(4)" ::: "memory");
  BAR();

  for (int t = 0; t < NT; t++) {
    const int buf = t & 1, nb = buf ^ 1;
    const bool st = (t + 1 < NT);
    const u16* As0 = &lds[buf][0][0][0];
    const u16* As1 = &lds[buf][0][1][0];
    const u16* Bs0 = &lds[buf][1][0][0];
    const u16* Bs1 = &lds[buf][1][1][0];

    bf16x8 av[8], bv[2];

    // ---- P0: A[kk0] + B01[kk0] ----
#pragma unroll
    for (int mi = 0; mi < 8; mi++)
      av[mi] = *(const bf16x8*)&As0[aoff + mi * 512];
    bv[0] = *(const bf16x8*)&Bs0[boff];
    bv[1] = *(const bf16x8*)&Bs0[boff + 512];
    if (st) STAGE_A(0, t + 1, nb);
    BAR();
    __builtin_amdgcn_s_setprio(1);
#pragma unroll
    for (int mi = 0; mi < 8; mi++) {
      acc[mi][0] = __builtin_amdgcn_mfma_f32_16x16x32_bf16(av[mi], bv[0], acc[mi][0], 0, 0, 0);
      acc[mi][1] = __builtin_amdgcn_mfma_f32_16x16x32_bf16(av[mi], bv[1], acc[mi][1], 0, 0, 0);
    }
    __builtin_amdgcn_s_setprio(0);
    BAR();

    // ---- P1: B23[kk0] ----
    bv[0] = *(const bf16x8*)&Bs0[boff + 1024];
    bv[1] = *(const bf16x8*)&Bs0[boff + 1536];
    if (st) STAGE_B(0, t + 1, nb);
    BAR();
    __builtin_amdgcn_s_setprio(1);
#pragma unroll
    for (int mi = 0; mi < 8; mi++) {
      acc[mi][2] = __builtin_amdgcn_mfma_f32_16x16x32_bf16(av[mi], bv[0], acc[mi][2], 0, 0, 0);
      acc[mi][3] = __builtin_amdgcn_mfma_f32_16x16x32_bf16(av[mi], bv[1], acc[mi][3], 0, 0, 0);
    }
    __builtin_amdgcn_s_setprio(0);
    if (t == NT - 1) asm volatile("s_waitcnt vmcnt(0)" ::: "memory");
    else             asm volatile("s_waitcnt vmcnt(4)" ::: "memory");
    BAR();   // certifies {A-khi,B-khi}(t)

    // ---- P2: A[kk1] + B01[kk1] ----
#pragma unroll
    for (int mi = 0; mi < 8; mi++)
      av[mi] = *(const bf16x8*)&As1[aoff + mi * 512];
    bv[0] = *(const bf16x8*)&Bs1[boff];
    bv[1] = *(const bf16x8*)&Bs1[boff + 512];
    if (st) STAGE_A(1, t + 1, nb);
    BAR();
    __builtin_amdgcn_s_setprio(1);
#pragma unroll
    for (int mi = 0; mi < 8; mi++) {
      acc[mi][0] = __builtin_amdgcn_mfma_f32_16x16x32_bf16(av[mi], bv[0], acc[mi][0], 0, 0, 0);
      acc[mi][1] = __builtin_amdgcn_mfma_f32_16x16x32_bf16(av[mi], bv[1], acc[mi][1], 0, 0, 0);
    }
    __builtin_amdgcn_s_setprio(0);
    BAR();

    // ---- P3: B23[kk1] ----
    bv[0] = *(const bf16x8*)&Bs1[boff + 1024];
    bv[1] = *(const bf16x8*)&Bs1[boff + 1536];
    if (st) STAGE_B(1, t + 1, nb);
    BAR();
    __builtin_amdgcn_s_setprio(1);
#pragma unroll
    for (int mi = 0; mi < 8; mi++) {
      acc[mi][2] = __builtin_amdgcn_mfma_f32_16x16x32_bf16(av[mi], bv[0], acc[mi][2], 0, 0, 0);
      acc[mi][3] = __builtin_amdgcn_mfma_f32_16x16x32_bf16(av[mi], bv[1], acc[mi][3], 0, 0, 0);
    }
    __builtin_amdgcn_s_setprio(0);
    asm volatile("s_waitcnt vmcnt(4)" ::: "memory");
    BAR();   // certifies {A-klo,B-klo}(t+1)
  }
#undef STAGE_A
#undef STAGE_B

  // C/D layout per 16x16 frag: col = lane&15, row = (lane>>4)*4 + reg
  const int crow0 = mt * 256 + wr * 128 + kg * 4;
  const int ccol0 = nt * 256 + wc * 64 + fr;
#pragma unroll
  for (int nj = 0; nj < 4; nj++) {
    const int col = ccol0 + nj * 16;
    const float bb = bias[col];
#pragma unroll
    for (int mi = 0; mi < 8; mi++) {
      const int r0 = crow0 + mi * 16;
      f32x4 v = acc[mi][nj];
#pragma unroll
      for (int r = 0; r < 4; r++)
        C[(size_t)(r0 + r) * N + col] = f2bu(v[r] + bb);
    }
  }
}

// ---------- tiny attention: S=3, 16 heads of d=64 ----------
__global__ __launch_bounds__(256) void attn3_kernel(
    const u16* __restrict__ qkv, u16* __restrict__ ctx) {
  const int tid = threadIdx.x;
  const int lane = tid & 63, wid = tid >> 6;
  const int unit = blockIdx.x * 4 + wid;
  const int b = unit >> 2, hg = unit & 3;
  const size_t qbase = (size_t)b * 3 * 3072 + hg * 256 + lane * 4;

  float q[3][4], k[3][4], v[3][4];
#pragma unroll
  for (int s = 0; s < 3; s++) {
    ushort4 uq = *(const ushort4*)(qkv + qbase + (size_t)s * 3072);
    ushort4 uk = *(const ushort4*)(qkv + qbase + (size_t)s * 3072 + 1024);
    ushort4 uv = *(const ushort4*)(qkv + qbase + (size_t)s * 3072 + 2048);
    q[s][0] = b2f(uq.x); q[s][1] = b2f(uq.y); q[s][2] = b2f(uq.z); q[s][3] = b2f(uq.w);
    k[s][0] = b2f(uk.x); k[s][1] = b2f(uk.y); k[s][2] = b2f(uk.z); k[s][3] = b2f(uk.w);
    v[s][0] = b2f(uv.x); v[s][1] = b2f(uv.y); v[s][2] = b2f(uv.z); v[s][3] = b2f(uv.w);
  }

  float sc[3][3];
#pragma unroll
  for (int i = 0; i < 3; i++)
#pragma unroll
    for (int j = 0; j < 3; j++) {
      float p = q[i][0] * k[j][0] + q[i][1] * k[j][1] +
                q[i][2] * k[j][2] + q[i][3] * k[j][3];
      p += __shfl_xor(p, 1);
      p += __shfl_xor(p, 2);
      p += __shfl_xor(p, 4);
      p += __shfl_xor(p, 8);   // 16-lane group = one head's 64 dims
      sc[i][j] = p;
    }

  float o[3][4];
#pragma unroll
  for (int i = 0; i < 3; i++) {
    float mx = fmaxf(sc[i][0], fmaxf(sc[i][1], sc[i][2]));
    float e0 = __expf((sc[i][0] - mx) * 0.125f);
    float e1 = __expf((sc[i][1] - mx) * 0.125f);
    float e2 = __expf((sc[i][2] - mx) * 0.125f);
    float inv = 1.f / (e0 + e1 + e2);
    e0 *= inv; e1 *= inv; e2 *= inv;
#pragma unroll
    for (int d = 0; d < 4; d++)
      o[i][d] = e0 * v[0][d] + e1 * v[1][d] + e2 * v[2][d];
  }

  const size_t obase = (size_t)b * 3 * 1024 + hg * 256 + lane * 4;
#pragma unroll
  for (int i = 0; i < 3; i++) {
    ushort4 ov;
    ov.x = f2bu(o[i][0]); ov.y = f2bu(o[i][1]);
    ov.z = f2bu(o[i][2]); ov.w = f2bu(o[i][3]);
    *(ushort4*)(ctx + obase + (size_t)i * 1024) = ov;
  }
}

// ---------- residual + LayerNorm: wave per row of 1024 ----------
__global__ __launch_bounds__(256) void ln_kernel(
    const float* __restrict__ slots, const u16* __restrict__ ao,
    const float* __restrict__ g, const float* __restrict__ bvec,
    float* __restrict__ out) {
  const int tid = threadIdx.x;
  const int lane = tid & 63, wid = tid >> 6;
  const int row = blockIdx.x * 4 + wid;
  const size_t rb = (size_t)row * 1024;

  float y[16];
  float sum = 0.f, sq = 0.f;
#pragma unroll
  for (int c = 0; c < 4; c++) {
    const int col = c * 256 + lane * 4;
    float4 sl = *(const float4*)(slots + rb + col);
    ushort4 a4 = *(const ushort4*)(ao + rb + col);
    float y0 = sl.x + b2f(a4.x), y1 = sl.y + b2f(a4.y);
    float y2 = sl.z + b2f(a4.z), y3 = sl.w + b2f(a4.w);
    y[c * 4 + 0] = y0; y[c * 4 + 1] = y1; y[c * 4 + 2] = y2; y[c * 4 + 3] = y3;
    sum += y0 + y1 + y2 + y3;
    sq += y0 * y0 + y1 * y1 + y2 * y2 + y3 * y3;
  }
#pragma unroll
  for (int m = 1; m < 64; m <<= 1) {
    sum += __shfl_xor(sum, m);
    sq  += __shfl_xor(sq, m);
  }
  const float mu = sum * (1.0f / 1024.0f);
  const float var = sq * (1.0f / 1024.0f) - mu * mu;
  const float rs = rsqrtf(var + 1e-5f);
#pragma unroll
  for (int c = 0; c < 4; c++) {
    const int col = c * 256 + lane * 4;
    float4 gg = *(const float4*)(g + col);
    float4 bb = *(const float4*)(bvec + col);
    float4 ov;
    ov.x = (y[c * 4 + 0] - mu) * rs * gg.x + bb.x;
    ov.y = (y[c * 4 + 1] - mu) * rs * gg.y + bb.y;
    ov.z = (y[c * 4 + 2] - mu) * rs * gg.z + bb.z;
    ov.w = (y[c * 4 + 3] - mu) * rs * gg.w + bb.w;
    *(float4*)(out + rb + col) = ov;
  }
}

extern "C" void kernel_launch(void* const* d_in, const int* in_sizes, int n_in,
                              void* d_out, int out_size, void* d_ws, size_t ws_size,
                              hipStream_t stream) {
  const float* slots = (const float*)d_in[0];
  const float* in_w  = (const float*)d_in[1];
  const float* in_b  = (const float*)d_in[2];
  const float* out_w = (const float*)d_in[3];
  const float* out_b = (const float*)d_in[4];
  const float* ln_g  = (const float*)d_in[5];
  const float* ln_b  = (const float*)d_in[6];
  float* out = (float*)d_out;

  const int M = 32768 * 3;  // 98304 rows

  // workspace layout (aliased):
  //   Abf   [M*1024 bf16] = 201,326,592 B   (later reused as ctx)
  //   Winb  [3072*1024]   =   6,291,456 B
  //   Woutb [1024*1024]   =   2,097,152 B
  //   qkv   [M*3072]      = 603,979,776 B   (first third later reused as attn_out)
  char* ws = (char*)d_ws;
  u16* Abf   = (u16*)ws;
  u16* Winb  = (u16*)(ws + 201326592);
  u16* Woutb = (u16*)(ws + 207618048);
  u16* qkv   = (u16*)(ws + 209715200);

  cvt_f32_bf16_kernel<<<2048, 256, 0, stream>>>(slots, Abf, M * 1024 / 4);
  cvt_f32_bf16_kernel<<<2048, 256, 0, stream>>>(in_w, Winb, 3072 * 1024 / 4);
  cvt_f32_bf16_kernel<<<1024, 256, 0, stream>>>(out_w, Woutb, 1024 * 1024 / 4);

  // qkv = Abf @ Winb^T + in_b : M x 3072, tiles 384 x 12
  gemm256_bt_bias<<<384 * 12, 512, 0, stream>>>(Abf, Winb, in_b, qkv, 3072, 1024, 12);

  // ctx (overwrites Abf)
  attn3_kernel<<<32768, 256, 0, stream>>>(qkv, Abf);

  // attn_out = ctx @ Woutb^T + out_b (overwrites start of qkv) : M x 1024, tiles 384 x 4
  gemm256_bt_bias<<<384 * 4, 512, 0, stream>>>(Abf, Woutb, out_b, qkv, 1024, 1024, 4);

  // out = LN(slots + attn_out) * g + b
  ln_kernel<<<M / 4, 256, 0, stream>>>(slots, qkv, ln_g, ln_b, out);
}